// Round 1
// baseline (874.871 us; speedup 1.0000x reference)
//
#include <hip/hip_runtime.h>
#include <stdint.h>

// Problem constants: B=8, H=12, D=64, S=1024
// scores[b,h,s,t] = sum_d K[b,h,d,s]*Q[b,h,d,t] / 8 ; mask over t ; softmax over t
// context[b,h,d,t] = sum_s V[b,h,d,s]*attn[b,h,s,t] ; out0[b][t][h*64+d], out1 = attn

typedef __attribute__((ext_vector_type(8))) short short8;
typedef __attribute__((ext_vector_type(4))) float floatx4;

#define DEVINL __device__ __forceinline__

DEVINL uint32_t f2u(float x) { union { float f; uint32_t u; } c; c.f = x; return c.u; }
DEVINL float u2f(uint32_t u) { union { uint32_t u; float f; } c; c.u = u; return c.f; }

// RNE fp32 -> bf16
DEVINL short cvt_bf16(float x) {
  uint32_t u = f2u(x);
  uint32_t r = u + 0x7FFFu + ((u >> 16) & 1u);
  return (short)(r >> 16);
}

// Split fp32 x into bf16 hi (RNE) and bf16 lo = RNE(x - hi). hi+lo == x to ~2^-17 rel.
DEVINL void split_bf16(float x, short &hi, short &lo) {
  uint32_t u = f2u(x);
  uint32_t r = u + 0x7FFFu + ((u >> 16) & 1u);
  hi = (short)(r >> 16);
  float hf = u2f(r & 0xFFFF0000u);
  float lf = x - hf;
  uint32_t v = f2u(lf);
  uint32_t r2 = v + 0x7FFFu + ((v >> 16) & 1u);
  lo = (short)(r2 >> 16);
}

// ---------------- kernel 0: Q[bh][d][t] fp32 -> QT[bh][t][{hi:64, lo:64}] bf16 ----------------
__global__ void k0_qtranspose(const float* __restrict__ Q, unsigned short* __restrict__ QT) {
  const int bh = blockIdx.y;
  const int t0 = blockIdx.x * 64;
  const int tid = threadIdx.x;
  __shared__ float tile[64][65];   // stride 65: only 2-way bank aliasing (free per m136)
  {
    const int d = tid >> 2;
    const int ts = (tid & 3) * 16;
    const float* src = Q + ((size_t)bh * 64 + d) * 1024 + t0 + ts;
    #pragma unroll
    for (int i = 0; i < 4; ++i) {
      float4 v = reinterpret_cast<const float4*>(src)[i];
      tile[d][ts + 4 * i + 0] = v.x;
      tile[d][ts + 4 * i + 1] = v.y;
      tile[d][ts + 4 * i + 2] = v.z;
      tile[d][ts + 4 * i + 3] = v.w;
    }
  }
  __syncthreads();
  {
    const int t = tid >> 2;
    const int dseg = (tid & 3) * 16;
    uint32_t hw[8], lw[8];
    #pragma unroll
    for (int jj = 0; jj < 8; ++jj) {
      short h0, l0, h1, l1;
      split_bf16(tile[dseg + 2 * jj + 0][t], h0, l0);
      split_bf16(tile[dseg + 2 * jj + 1][t], h1, l1);
      hw[jj] = (uint32_t)(uint16_t)h0 | ((uint32_t)(uint16_t)h1 << 16);
      lw[jj] = (uint32_t)(uint16_t)l0 | ((uint32_t)(uint16_t)l1 << 16);
    }
    unsigned short* orow = QT + ((size_t)bh * 1024 + t0 + t) * 128;
    uint4* oh = reinterpret_cast<uint4*>(orow + dseg);
    oh[0] = make_uint4(hw[0], hw[1], hw[2], hw[3]);
    oh[1] = make_uint4(hw[4], hw[5], hw[6], hw[7]);
    uint4* ol = reinterpret_cast<uint4*>(orow + 64 + dseg);
    ol[0] = make_uint4(lw[0], lw[1], lw[2], lw[3]);
    ol[1] = make_uint4(lw[4], lw[5], lw[6], lw[7]);
  }
}

// ---------------- kernel 0b: V fp32 -> bf16 (layout preserved), kills per-iter cvt in k2 ------
__global__ void k0b_vcast(const float* __restrict__ V, unsigned short* __restrict__ VB) {
  const size_t i = ((size_t)blockIdx.x * 256 + threadIdx.x) * 8;
  float4 a = *reinterpret_cast<const float4*>(V + i);
  float4 b = *reinterpret_cast<const float4*>(V + i + 4);
  short8 o;
  o[0] = cvt_bf16(a.x); o[1] = cvt_bf16(a.y); o[2] = cvt_bf16(a.z); o[3] = cvt_bf16(a.w);
  o[4] = cvt_bf16(b.x); o[5] = cvt_bf16(b.y); o[6] = cvt_bf16(b.z); o[7] = cvt_bf16(b.w);
  *reinterpret_cast<short8*>(VB + i) = o;
}

// ---------------- kernel 1: scores = K^T Q /8, mask, exp (no max), norm, write attn fp32 ------
// TWO-PASS RECOMPUTE: pass1 computes row-sums with a single floatx4 acc (reused per nf),
// pass2 recomputes scores and writes normalized attn. Drops live state 64->~8 regs so we can
// run 8 waves/EU (was 4) — k1 was latency-bound (MfmaUtil 5.7%, VALU 13%, HBM 24%, Occ 45%).
// MFMA cost doubles (5.7%->~11% util, cheap); QT re-read is L2-resident (3 MB/XCD).
// grid (96 bh, 64 sblk): x = bh so same-bh blocks share one XCD's L2 (96 % 8 == 0).
__global__ __launch_bounds__(256, 8)
void k1_scores_softmax(const float* __restrict__ Kt, const int* __restrict__ masks,
                       const unsigned short* __restrict__ QT, float* __restrict__ attn) {
  const int bh = blockIdx.x;
  const int b = bh / 12;
  const int s0 = blockIdx.y * 16;
  const int tid = threadIdx.x;
  const int w = tid >> 6, lane = tid & 63;
  const int q = lane >> 4, l15 = lane & 15;

  // A = K^T fragments: A[m=s][k=d], lane row m=l15, k = kk*32 + q*8 + j. Loaded once, held.
  short8 ahi[2], alo[2];
  {
    const float* Kp = Kt + (size_t)bh * 65536 + s0 + l15;
    #pragma unroll
    for (int kk = 0; kk < 2; ++kk)
      #pragma unroll
      for (int j = 0; j < 8; ++j) {
        short h, l;
        split_bf16(Kp[(size_t)(kk * 32 + q * 8 + j) * 1024], h, l);
        ahi[kk][j] = h; alo[kk][j] = l;
      }
  }

  const int* mrow = masks + b * 1024;
  uint32_t mkbits = 0;
  #pragma unroll
  for (int nf = 0; nf < 16; ++nf)
    mkbits |= (mrow[w * 256 + nf * 16 + l15] != 0 ? 1u : 0u) << nf;

  const unsigned short* QTb = QT + (size_t)bh * 131072;

  // ---- pass 1: row sums only (acc reused each nf) ----
  float sm[4] = {0.f, 0.f, 0.f, 0.f};
  #pragma unroll 2
  for (int nf = 0; nf < 16; ++nf) {
    const int t = w * 256 + nf * 16 + l15;
    const unsigned short* row = QTb + (size_t)t * 128 + q * 8;
    floatx4 acc = (floatx4){0.f, 0.f, 0.f, 0.f};
    #pragma unroll
    for (int kk = 0; kk < 2; ++kk) {
      short8 bhh = *reinterpret_cast<const short8*>(row + kk * 32);       // Q hi
      short8 bll = *reinterpret_cast<const short8*>(row + 64 + kk * 32);  // Q lo
      acc = __builtin_amdgcn_mfma_f32_16x16x32_bf16(ahi[kk], bhh, acc, 0, 0, 0);
      acc = __builtin_amdgcn_mfma_f32_16x16x32_bf16(alo[kk], bhh, acc, 0, 0, 0);
      acc = __builtin_amdgcn_mfma_f32_16x16x32_bf16(ahi[kk], bll, acc, 0, 0, 0);
    }
    const bool mk = (mkbits >> nf) & 1u;
    #pragma unroll
    for (int r = 0; r < 4; ++r)
      sm[r] += mk ? __expf(acc[r] * 0.125f) : 0.0f;
  }

  // C/D layout: col t = l15, row s_local = q*4 + r. Reduce over the 16 t-lanes.
  #pragma unroll
  for (int r = 0; r < 4; ++r)
    #pragma unroll
    for (int off = 1; off < 16; off <<= 1)
      sm[r] += __shfl_xor(sm[r], off, 16);

  __shared__ float redsum[4][16];
  if (l15 == 0) {
    #pragma unroll
    for (int r = 0; r < 4; ++r) redsum[w][q * 4 + r] = sm[r];
  }
  __syncthreads();
  float inv[4];
  #pragma unroll
  for (int r = 0; r < 4; ++r)
    inv[r] = 1.0f / (redsum[0][q * 4 + r] + redsum[1][q * 4 + r] +
                     redsum[2][q * 4 + r] + redsum[3][q * 4 + r]);

  // ---- pass 2: recompute, normalize, store ----
  float* arow = attn + (size_t)bh * 1048576 + (size_t)s0 * 1024;
  #pragma unroll 2
  for (int nf = 0; nf < 16; ++nf) {
    const int t = w * 256 + nf * 16 + l15;
    const unsigned short* row = QTb + (size_t)t * 128 + q * 8;
    floatx4 acc = (floatx4){0.f, 0.f, 0.f, 0.f};
    #pragma unroll
    for (int kk = 0; kk < 2; ++kk) {
      short8 bhh = *reinterpret_cast<const short8*>(row + kk * 32);
      short8 bll = *reinterpret_cast<const short8*>(row + 64 + kk * 32);
      acc = __builtin_amdgcn_mfma_f32_16x16x32_bf16(ahi[kk], bhh, acc, 0, 0, 0);
      acc = __builtin_amdgcn_mfma_f32_16x16x32_bf16(alo[kk], bhh, acc, 0, 0, 0);
      acc = __builtin_amdgcn_mfma_f32_16x16x32_bf16(ahi[kk], bll, acc, 0, 0, 0);
    }
    const bool mk = (mkbits >> nf) & 1u;
    #pragma unroll
    for (int r = 0; r < 4; ++r) {
      float o = mk ? __expf(acc[r] * 0.125f) * inv[r] : 0.0f;
      arow[(size_t)(q * 4 + r) * 1024 + t] = o;
    }
  }
}

// ---------------- kernel 2: context[d,t] = sum_s V[d,s] * attn[s,t] -> out[b][t][h*64+d] ------
// attn B-fragments now come from an LDS-staged [32 s][128 t] fp32 tile:
//  - staging loads are fully coalesced (two 512B rows per wave instruction)
//  - double-buffered, T14 split: global loads issued BEFORE the barrier, ds_write after
//  - XOR swizzle (bit4 ^= s-bit3) -> fragment ds_read_b32 worst 2-way bank alias (free),
//    staging ds_write_b128 conflict-free (8 dwords/bank = minimum)
// grid (96 bh, 8 tblk): x = bh so the 8 blocks re-reading one V slice share an XCD L2.
__global__ __launch_bounds__(256, 4)
void k2_pv(const unsigned short* __restrict__ VB, const float* __restrict__ attn,
           float* __restrict__ ctx) {
  const int bh = blockIdx.x;
  const int b = bh / 12, h = bh % 12;
  const int t0 = blockIdx.y * 128;
  const int tid = threadIdx.x;
  const int wave = tid >> 6, lane = tid & 63;
  const int q = lane >> 4, l15 = lane & 15;

  __shared__ float att[2][32 * 128];   // 2 x 16KB

  const float* Ab = attn + (size_t)bh * 1048576 + t0;
  const unsigned short* Vb = VB + (size_t)bh * 65536;

  const int srow = tid >> 5;        // 0..7
  const int scol = (tid & 31) * 4;  // dword col 0..124

  floatx4 acc[4][2];
  #pragma unroll
  for (int i = 0; i < 4; ++i)
    #pragma unroll
    for (int j = 0; j < 2; ++j) acc[i][j] = (floatx4){0.f, 0.f, 0.f, 0.f};

  float4 r0, r1, r2, r3;
  {
    const float* p = Ab + (size_t)srow * 1024 + scol;
    r0 = *reinterpret_cast<const float4*>(p);
    r1 = *reinterpret_cast<const float4*>(p + 8 * 1024);
    r2 = *reinterpret_cast<const float4*>(p + 16 * 1024);
    r3 = *reinterpret_cast<const float4*>(p + 24 * 1024);
  }
  // swizzled LDS write: dword col ^= ((row>>3)&1)<<4 ; float4 stays aligned (XOR bit >= 4 dwords)
  #define WSWZ(bufp, v, rowi)                                                   \
    *reinterpret_cast<float4*>((bufp) + (rowi) * 128 +                          \
                               (scol ^ ((((rowi) >> 3) & 1) << 4))) = (v)
  WSWZ(att[0], r0, srow); WSWZ(att[0], r1, srow + 8);
  WSWZ(att[0], r2, srow + 16); WSWZ(att[0], r3, srow + 24);

  int cur = 0;
  for (int it = 0; it < 32; ++it) {
    const int s0 = it * 32;
    if (it < 31) {  // issue-early: loads in flight across the barrier + compute
      const float* p = Ab + (size_t)(s0 + 32 + srow) * 1024 + scol;
      r0 = *reinterpret_cast<const float4*>(p);
      r1 = *reinterpret_cast<const float4*>(p + 8 * 1024);
      r2 = *reinterpret_cast<const float4*>(p + 16 * 1024);
      r3 = *reinterpret_cast<const float4*>(p + 24 * 1024);
    }
    __syncthreads();  // att[cur] staging visible

    // A = V fragments: m = mf*16+l15 (d), k = s0+q*8+j — bf16 direct, one 16B load each.
    short8 va[4];
    #pragma unroll
    for (int mf = 0; mf < 4; ++mf)
      va[mf] = *reinterpret_cast<const short8*>(Vb + (size_t)(mf * 16 + l15) * 1024 + s0 + q * 8);

    // B = attn fragments from LDS: s_local = q*8+j, t_local = wave*32+nf*16+l15 (swizzled).
    short8 pa[2];
    const float* buf = att[cur];
    #pragma unroll
    for (int nf = 0; nf < 2; ++nf) {
      const int tswz = (wave * 32 + nf * 16 + l15) ^ ((q & 1) << 4);
      #pragma unroll
      for (int j = 0; j < 8; ++j)
        pa[nf][j] = cvt_bf16(buf[(q * 8 + j) * 128 + tswz]);
    }

    #pragma unroll
    for (int mf = 0; mf < 4; ++mf)
      #pragma unroll
      for (int nf = 0; nf < 2; ++nf)
        acc[mf][nf] = __builtin_amdgcn_mfma_f32_16x16x32_bf16(va[mf], pa[nf], acc[mf][nf], 0, 0, 0);

    if (it < 31) {  // write-late into the other buffer (safe: all waves passed this iter's barrier)
      float* nb = att[cur ^ 1];
      WSWZ(nb, r0, srow); WSWZ(nb, r1, srow + 8);
      WSWZ(nb, r2, srow + 16); WSWZ(nb, r3, srow + 24);
    }
    cur ^= 1;
  }
  #undef WSWZ

  const int twave = t0 + wave * 32;
  #pragma unroll
  for (int mf = 0; mf < 4; ++mf)
    #pragma unroll
    for (int nf = 0; nf < 2; ++nf) {
      const int t = twave + nf * 16 + l15;
      const int d0 = mf * 16 + q * 4;                 // rows = q*4+r (consecutive d) -> float4
      float* op = ctx + ((size_t)b * 1024 + t) * 768 + h * 64 + d0;
      *reinterpret_cast<floatx4*>(op) = acc[mf][nf];
    }
}

extern "C" void kernel_launch(void* const* d_in, const int* in_sizes, int n_in,
                              void* d_out, int out_size, void* d_ws, size_t ws_size,
                              hipStream_t stream) {
  const float* Q = (const float*)d_in[0];
  const float* K = (const float*)d_in[1];
  const float* V = (const float*)d_in[2];
  const int* masks = (const int*)d_in[3];
  float* ctx = (float*)d_out;                               // (8,1024,768) fp32
  float* attn = (float*)d_out + (size_t)8 * 1024 * 768;     // (8,12,1024,1024) fp32
  unsigned short* QT = (unsigned short*)d_ws;               // 96*1024*128 bf16 = 25.2 MB
  unsigned short* VB = (unsigned short*)d_ws + (size_t)96 * 1024 * 128;  // 12.6 MB

  k0_qtranspose<<<dim3(16, 96), 256, 0, stream>>>(Q, QT);
  k0b_vcast<<<3072, 256, 0, stream>>>(V, VB);
  k1_scores_softmax<<<dim3(96, 64), 256, 0, stream>>>(K, masks, QT, attn);
  k2_pv<<<dim3(96, 8), 256, 0, stream>>>(VB, attn, ctx);
}

// Round 2
// 743.076 us; speedup vs baseline: 1.1774x; 1.1774x over previous
//
#include <hip/hip_runtime.h>
#include <stdint.h>

// Problem constants: B=8, H=12, D=64, S=1024
// scores[b,h,s,t] = sum_d K[b,h,d,s]*Q[b,h,d,t] / 8 ; mask over t ; softmax over t
// context[b,h,d,t] = sum_s V[b,h,d,s]*attn[b,h,s,t] ; out0[b][t][h*64+d], out1 = attn

typedef __attribute__((ext_vector_type(8))) short short8;
typedef __attribute__((ext_vector_type(4))) float floatx4;

#define DEVINL __device__ __forceinline__

DEVINL uint32_t f2u(float x) { union { float f; uint32_t u; } c; c.f = x; return c.u; }
DEVINL float u2f(uint32_t u) { union { uint32_t u; float f; } c; c.u = u; return c.f; }

// RNE fp32 -> bf16
DEVINL short cvt_bf16(float x) {
  uint32_t u = f2u(x);
  uint32_t r = u + 0x7FFFu + ((u >> 16) & 1u);
  return (short)(r >> 16);
}

// Split fp32 x into bf16 hi (RNE) and bf16 lo = RNE(x - hi). hi+lo == x to ~2^-17 rel.
DEVINL void split_bf16(float x, short &hi, short &lo) {
  uint32_t u = f2u(x);
  uint32_t r = u + 0x7FFFu + ((u >> 16) & 1u);
  hi = (short)(r >> 16);
  float hf = u2f(r & 0xFFFF0000u);
  float lf = x - hf;
  uint32_t v = f2u(lf);
  uint32_t r2 = v + 0x7FFFu + ((v >> 16) & 1u);
  lo = (short)(r2 >> 16);
}

// ---------------- kernel 0: Q[bh][d][t] fp32 -> QT[bh][t][{hi:64, lo:64}] bf16 ----------------
__global__ void k0_qtranspose(const float* __restrict__ Q, unsigned short* __restrict__ QT) {
  const int bh = blockIdx.y;
  const int t0 = blockIdx.x * 64;
  const int tid = threadIdx.x;
  __shared__ float tile[64][65];   // stride 65: only 2-way bank aliasing (free per m136)
  {
    const int d = tid >> 2;
    const int ts = (tid & 3) * 16;
    const float* src = Q + ((size_t)bh * 64 + d) * 1024 + t0 + ts;
    #pragma unroll
    for (int i = 0; i < 4; ++i) {
      float4 v = reinterpret_cast<const float4*>(src)[i];
      tile[d][ts + 4 * i + 0] = v.x;
      tile[d][ts + 4 * i + 1] = v.y;
      tile[d][ts + 4 * i + 2] = v.z;
      tile[d][ts + 4 * i + 3] = v.w;
    }
  }
  __syncthreads();
  {
    const int t = tid >> 2;
    const int dseg = (tid & 3) * 16;
    uint32_t hw[8], lw[8];
    #pragma unroll
    for (int jj = 0; jj < 8; ++jj) {
      short h0, l0, h1, l1;
      split_bf16(tile[dseg + 2 * jj + 0][t], h0, l0);
      split_bf16(tile[dseg + 2 * jj + 1][t], h1, l1);
      hw[jj] = (uint32_t)(uint16_t)h0 | ((uint32_t)(uint16_t)h1 << 16);
      lw[jj] = (uint32_t)(uint16_t)l0 | ((uint32_t)(uint16_t)l1 << 16);
    }
    unsigned short* orow = QT + ((size_t)bh * 1024 + t0 + t) * 128;
    uint4* oh = reinterpret_cast<uint4*>(orow + dseg);
    oh[0] = make_uint4(hw[0], hw[1], hw[2], hw[3]);
    oh[1] = make_uint4(hw[4], hw[5], hw[6], hw[7]);
    uint4* ol = reinterpret_cast<uint4*>(orow + 64 + dseg);
    ol[0] = make_uint4(lw[0], lw[1], lw[2], lw[3]);
    ol[1] = make_uint4(lw[4], lw[5], lw[6], lw[7]);
  }
}

// ---------------- kernel 0b: V fp32 -> bf16 (layout preserved), kills per-iter cvt in k2 ------
__global__ void k0b_vcast(const float* __restrict__ V, unsigned short* __restrict__ VB) {
  const size_t i = ((size_t)blockIdx.x * 256 + threadIdx.x) * 8;
  float4 a = *reinterpret_cast<const float4*>(V + i);
  float4 b = *reinterpret_cast<const float4*>(V + i + 4);
  short8 o;
  o[0] = cvt_bf16(a.x); o[1] = cvt_bf16(a.y); o[2] = cvt_bf16(a.z); o[3] = cvt_bf16(a.w);
  o[4] = cvt_bf16(b.x); o[5] = cvt_bf16(b.y); o[6] = cvt_bf16(b.z); o[7] = cvt_bf16(b.w);
  *reinterpret_cast<short8*>(VB + i) = o;
}

// ---------------- kernel 1: scores = K^T Q /8, mask, exp (no max), norm, write attn fp32 ------
// Round-0 single-pass core (proven 274 us) + NEW LDS-transposed epilogue:
// the MFMA C/D layout scatters direct stores into 4x64B segments at 4KB stride, which ran at
// ~1.65 TB/s effective. Round-trip each 16x512 t-half through LDS so every global store is a
// 1KB-contiguous dwordx4 (fill kernel proves this pattern runs at 6.2 TB/s).
// LDS write: addr=(q*4+r)*516+t_local: bank=(8*(q&1)*2+l15)%32 -> 2 lanes/bank = free (m136).
// grid (96 bh, 64 sblk): x = bh so same-bh blocks share one XCD's L2 (96 % 8 == 0).
__global__ __launch_bounds__(256, 4)
void k1_scores_softmax(const float* __restrict__ Kt, const int* __restrict__ masks,
                       const unsigned short* __restrict__ QT, float* __restrict__ attn) {
  const int bh = blockIdx.x;
  const int b = bh / 12;
  const int s0 = blockIdx.y * 16;
  const int tid = threadIdx.x;
  const int w = tid >> 6, lane = tid & 63;
  const int q = lane >> 4, l15 = lane & 15;

  // A = K^T fragments: A[m=s][k=d], lane row m=l15, k = kk*32 + q*8 + j. Loaded once, split.
  short8 ahi[2], alo[2];
  {
    const float* Kp = Kt + (size_t)bh * 65536 + s0 + l15;
    #pragma unroll
    for (int kk = 0; kk < 2; ++kk)
      #pragma unroll
      for (int j = 0; j < 8; ++j) {
        short h, l;
        split_bf16(Kp[(size_t)(kk * 32 + q * 8 + j) * 1024], h, l);
        ahi[kk][j] = h; alo[kk][j] = l;
      }
  }

  // Pre-read mask bits for this lane's 16 t values (overlaps with MFMA loop).
  const int* mrow = masks + b * 1024;
  uint32_t mkbits = 0;
  #pragma unroll
  for (int nf = 0; nf < 16; ++nf)
    mkbits |= (mrow[w * 256 + nf * 16 + l15] != 0 ? 1u : 0u) << nf;

  floatx4 acc[16];
  #pragma unroll
  for (int i = 0; i < 16; ++i) acc[i] = (floatx4){0.f, 0.f, 0.f, 0.f};

  const unsigned short* QTb = QT + (size_t)bh * 131072;
  #pragma unroll
  for (int nf = 0; nf < 16; ++nf) {
    const int t = w * 256 + nf * 16 + l15;
    const unsigned short* row = QTb + (size_t)t * 128 + q * 8;
    #pragma unroll
    for (int kk = 0; kk < 2; ++kk) {
      short8 bhh = *reinterpret_cast<const short8*>(row + kk * 32);       // Q hi
      short8 bll = *reinterpret_cast<const short8*>(row + 64 + kk * 32);  // Q lo
      acc[nf] = __builtin_amdgcn_mfma_f32_16x16x32_bf16(ahi[kk], bhh, acc[nf], 0, 0, 0);
      acc[nf] = __builtin_amdgcn_mfma_f32_16x16x32_bf16(alo[kk], bhh, acc[nf], 0, 0, 0);
      acc[nf] = __builtin_amdgcn_mfma_f32_16x16x32_bf16(ahi[kk], bll, acc[nf], 0, 0, 0);
    }
  }

  // exp + per-row sum. C/D layout: col t = l15, row s_local = q*4 + r.
  float sm[4] = {0.f, 0.f, 0.f, 0.f};
  #pragma unroll
  for (int nf = 0; nf < 16; ++nf) {
    const bool mk = (mkbits >> nf) & 1u;
    #pragma unroll
    for (int r = 0; r < 4; ++r) {
      float e = mk ? __expf(acc[nf][r] * 0.125f) : 0.0f;
      acc[nf][r] = e;
      sm[r] += e;
    }
  }
  #pragma unroll
  for (int r = 0; r < 4; ++r)
    #pragma unroll
    for (int off = 1; off < 16; off <<= 1)
      sm[r] += __shfl_xor(sm[r], off, 16);

  __shared__ float redsum[4][16];
  if (l15 == 0) {
    #pragma unroll
    for (int r = 0; r < 4; ++r) redsum[w][q * 4 + r] = sm[r];
  }
  __syncthreads();
  float inv[4];
  #pragma unroll
  for (int r = 0; r < 4; ++r)
    inv[r] = 1.0f / (redsum[0][q * 4 + r] + redsum[1][q * 4 + r] +
                     redsum[2][q * 4 + r] + redsum[3][q * 4 + r]);

  // ---- LDS-transposed store: two t-halves of 512, each staged as [16 s][516] fp32 ----
  __shared__ float xpose[16][516];   // 33.0 KB; stride 516: write = 2-way bank alias (free)
  float* arow = attn + (size_t)bh * 1048576 + (size_t)s0 * 1024;
  #pragma unroll
  for (int half = 0; half < 2; ++half) {
    __syncthreads();                 // protect xpose reuse across halves
    if ((w >> 1) == half) {          // waves owning this t-half dump their normalized tile
      const int wl = w & 1;
      #pragma unroll
      for (int nf = 0; nf < 16; ++nf)
        #pragma unroll
        for (int r = 0; r < 4; ++r)
          xpose[q * 4 + r][wl * 256 + nf * 16 + l15] = acc[nf][r] * inv[r];
    }
    __syncthreads();
    // all 4 waves store: wave w -> rows w*4..w*4+3; each instr = 64 lanes x float4 = 1KB contig
    #pragma unroll
    for (int rr = 0; rr < 4; ++rr) {
      const int row = w * 4 + rr;
      #pragma unroll
      for (int c = 0; c < 2; ++c) {
        float4 v = *reinterpret_cast<const float4*>(&xpose[row][c * 256 + lane * 4]);
        *reinterpret_cast<float4*>(arow + (size_t)row * 1024 + half * 512 + c * 256 + lane * 4) = v;
      }
    }
  }
}

// ---------------- kernel 2: context[d,t] = sum_s V[d,s] * attn[s,t] -> out[b][t][h*64+d] ------
// attn B-fragments from LDS-staged [32 s][128 t] fp32 tiles (coalesced 512B rows, dbuf, T14
// issue-early/write-late, bit4 XOR swizzle -> ds reads 2-way alias = free).
// s-reduction split over gridDim.z (z*iters*32 base): 2x blocks -> ~5 blocks/CU (was 3),
// more HBM bytes in flight. z=0 writes ctx, z=1 writes partial P; k3 adds.
// grid (96 bh, 8 tblk, z): x = bh so blocks sharing a V slice land on one XCD (96 % 8 == 0).
__global__ __launch_bounds__(256, 4)
void k2_pv(const unsigned short* __restrict__ VB, const float* __restrict__ attn,
           float* __restrict__ out0, float* __restrict__ out1, int iters) {
  const int bh = blockIdx.x;
  const int b = bh / 12, h = bh % 12;
  const int t0 = blockIdx.y * 128;
  const int z = blockIdx.z;
  float* __restrict__ outp = (z == 0) ? out0 : out1;
  const int s_base = z * iters * 32;
  const int tid = threadIdx.x;
  const int wave = tid >> 6, lane = tid & 63;
  const int q = lane >> 4, l15 = lane & 15;

  __shared__ float att[2][32 * 128];   // 2 x 16KB

  const float* Ab = attn + (size_t)bh * 1048576 + t0;
  const unsigned short* Vb = VB + (size_t)bh * 65536;

  const int srow = tid >> 5;        // 0..7
  const int scol = (tid & 31) * 4;  // dword col 0..124

  floatx4 acc[4][2];
  #pragma unroll
  for (int i = 0; i < 4; ++i)
    #pragma unroll
    for (int j = 0; j < 2; ++j) acc[i][j] = (floatx4){0.f, 0.f, 0.f, 0.f};

  float4 r0, r1, r2, r3;
  {
    const float* p = Ab + (size_t)(s_base + srow) * 1024 + scol;
    r0 = *reinterpret_cast<const float4*>(p);
    r1 = *reinterpret_cast<const float4*>(p + 8 * 1024);
    r2 = *reinterpret_cast<const float4*>(p + 16 * 1024);
    r3 = *reinterpret_cast<const float4*>(p + 24 * 1024);
  }
  // swizzled LDS write: dword col ^= ((row>>3)&1)<<4 ; float4 stays aligned (XOR bit >= 4 dwords)
  #define WSWZ(bufp, v, rowi)                                                   \
    *reinterpret_cast<float4*>((bufp) + (rowi) * 128 +                          \
                               (scol ^ ((((rowi) >> 3) & 1) << 4))) = (v)
  WSWZ(att[0], r0, srow); WSWZ(att[0], r1, srow + 8);
  WSWZ(att[0], r2, srow + 16); WSWZ(att[0], r3, srow + 24);

  int cur = 0;
  for (int it = 0; it < iters; ++it) {
    const int s0 = s_base + it * 32;
    if (it < iters - 1) {  // issue-early: loads in flight across the barrier + compute
      const float* p = Ab + (size_t)(s0 + 32 + srow) * 1024 + scol;
      r0 = *reinterpret_cast<const float4*>(p);
      r1 = *reinterpret_cast<const float4*>(p + 8 * 1024);
      r2 = *reinterpret_cast<const float4*>(p + 16 * 1024);
      r3 = *reinterpret_cast<const float4*>(p + 24 * 1024);
    }
    __syncthreads();  // att[cur] staging visible

    // A = V fragments: m = mf*16+l15 (d), k = s0+q*8+j — bf16 direct, one 16B load each.
    short8 va[4];
    #pragma unroll
    for (int mf = 0; mf < 4; ++mf)
      va[mf] = *reinterpret_cast<const short8*>(Vb + (size_t)(mf * 16 + l15) * 1024 + s0 + q * 8);

    // B = attn fragments from LDS: s_local = q*8+j, t_local = wave*32+nf*16+l15 (swizzled).
    short8 pa[2];
    const float* buf = att[cur];
    #pragma unroll
    for (int nf = 0; nf < 2; ++nf) {
      const int tswz = (wave * 32 + nf * 16 + l15) ^ ((q & 1) << 4);
      #pragma unroll
      for (int j = 0; j < 8; ++j)
        pa[nf][j] = cvt_bf16(buf[(q * 8 + j) * 128 + tswz]);
    }

    #pragma unroll
    for (int mf = 0; mf < 4; ++mf)
      #pragma unroll
      for (int nf = 0; nf < 2; ++nf)
        acc[mf][nf] = __builtin_amdgcn_mfma_f32_16x16x32_bf16(va[mf], pa[nf], acc[mf][nf], 0, 0, 0);

    if (it < iters - 1) {  // write-late into the other buffer (all waves passed this barrier)
      float* nb = att[cur ^ 1];
      WSWZ(nb, r0, srow); WSWZ(nb, r1, srow + 8);
      WSWZ(nb, r2, srow + 16); WSWZ(nb, r3, srow + 24);
    }
    cur ^= 1;
  }
  #undef WSWZ

  const int twave = t0 + wave * 32;
  #pragma unroll
  for (int mf = 0; mf < 4; ++mf)
    #pragma unroll
    for (int nf = 0; nf < 2; ++nf) {
      const int t = twave + nf * 16 + l15;
      const int d0 = mf * 16 + q * 4;                 // rows = q*4+r (consecutive d) -> float4
      float* op = outp + ((size_t)b * 1024 + t) * 768 + h * 64 + d0;
      *reinterpret_cast<floatx4*>(op) = acc[mf][nf];
    }
}

// ---------------- kernel 3: ctx += P (only when s-split is active) ----------------------------
__global__ void k3_add(float* __restrict__ ctx, const float* __restrict__ P) {
  const size_t i = ((size_t)blockIdx.x * 256 + threadIdx.x) * 4;
  float4 a = *reinterpret_cast<const float4*>(ctx + i);
  float4 p = *reinterpret_cast<const float4*>(P + i);
  a.x += p.x; a.y += p.y; a.z += p.z; a.w += p.w;
  *reinterpret_cast<float4*>(ctx + i) = a;
}

extern "C" void kernel_launch(void* const* d_in, const int* in_sizes, int n_in,
                              void* d_out, int out_size, void* d_ws, size_t ws_size,
                              hipStream_t stream) {
  const float* Q = (const float*)d_in[0];
  const float* K = (const float*)d_in[1];
  const float* V = (const float*)d_in[2];
  const int* masks = (const int*)d_in[3];
  float* ctx = (float*)d_out;                               // (8,1024,768) fp32
  float* attn = (float*)d_out + (size_t)8 * 1024 * 768;     // (8,12,1024,1024) fp32

  const size_t QT_BYTES = (size_t)96 * 1024 * 128 * 2;      // 25.2 MB
  const size_t VB_BYTES = (size_t)96 * 64 * 1024 * 2;       // 12.6 MB
  const size_t P_BYTES  = (size_t)8 * 1024 * 768 * 4;       // 25.2 MB
  unsigned short* QT = (unsigned short*)d_ws;
  unsigned short* VB = (unsigned short*)((char*)d_ws + QT_BYTES);
  float* P = (float*)((char*)d_ws + QT_BYTES + VB_BYTES);
  const bool split = ws_size >= QT_BYTES + VB_BYTES + P_BYTES;

  k0_qtranspose<<<dim3(16, 96), 256, 0, stream>>>(Q, QT);
  k0b_vcast<<<3072, 256, 0, stream>>>(V, VB);
  k1_scores_softmax<<<dim3(96, 64), 256, 0, stream>>>(K, masks, QT, attn);
  if (split) {
    k2_pv<<<dim3(96, 8, 2), 256, 0, stream>>>(VB, attn, ctx, P, 16);
    k3_add<<<6144, 256, 0, stream>>>(ctx, P);
  } else {
    k2_pv<<<dim3(96, 8, 1), 256, 0, stream>>>(VB, attn, ctx, ctx, 32);
  }
}

// Round 3
// 731.915 us; speedup vs baseline: 1.1953x; 1.0152x over previous
//
#include <hip/hip_runtime.h>
#include <stdint.h>

// Problem constants: B=8, H=12, D=64, S=1024
// scores[b,h,s,t] = sum_d K[b,h,d,s]*Q[b,h,d,t] / 8 ; mask over t ; softmax over t
// context[b,h,d,t] = sum_s V[b,h,d,s]*attn[b,h,s,t] ; out0[b][t][h*64+d], out1 = attn

typedef __attribute__((ext_vector_type(8))) short short8;
typedef __attribute__((ext_vector_type(4))) float floatx4;

#define DEVINL __device__ __forceinline__

DEVINL uint32_t f2u(float x) { union { float f; uint32_t u; } c; c.f = x; return c.u; }
DEVINL float u2f(uint32_t u) { union { uint32_t u; float f; } c; c.u = u; return c.f; }

// RNE fp32 -> bf16
DEVINL short cvt_bf16(float x) {
  uint32_t u = f2u(x);
  uint32_t r = u + 0x7FFFu + ((u >> 16) & 1u);
  return (short)(r >> 16);
}

// Split fp32 x into bf16 hi (RNE) and bf16 lo = RNE(x - hi). hi+lo == x to ~2^-17 rel.
DEVINL void split_bf16(float x, short &hi, short &lo) {
  uint32_t u = f2u(x);
  uint32_t r = u + 0x7FFFu + ((u >> 16) & 1u);
  hi = (short)(r >> 16);
  float hf = u2f(r & 0xFFFF0000u);
  float lf = x - hf;
  uint32_t v = f2u(lf);
  uint32_t r2 = v + 0x7FFFu + ((v >> 16) & 1u);
  lo = (short)(r2 >> 16);
}

// async global->LDS, 16B per lane. Dest must be wave-uniform base; HW writes lane i at base+i*16.
typedef const __attribute__((address_space(1))) unsigned int gas_u32;
typedef __attribute__((address_space(3))) unsigned int las_u32;
DEVINL void gll16(const void* g, void* l) {
  __builtin_amdgcn_global_load_lds((gas_u32*)g, (las_u32*)l, 16, 0, 0);
}

// ---------------- kernel 0: Q[bh][d][t] fp32 -> QT[bh][t][{hi:64, lo:64}] bf16 ----------------
__global__ void k0_qtranspose(const float* __restrict__ Q, unsigned short* __restrict__ QT) {
  const int bh = blockIdx.y;
  const int t0 = blockIdx.x * 64;
  const int tid = threadIdx.x;
  __shared__ float tile[64][65];   // stride 65: only 2-way bank aliasing (free per m136)
  {
    const int d = tid >> 2;
    const int ts = (tid & 3) * 16;
    const float* src = Q + ((size_t)bh * 64 + d) * 1024 + t0 + ts;
    #pragma unroll
    for (int i = 0; i < 4; ++i) {
      float4 v = reinterpret_cast<const float4*>(src)[i];
      tile[d][ts + 4 * i + 0] = v.x;
      tile[d][ts + 4 * i + 1] = v.y;
      tile[d][ts + 4 * i + 2] = v.z;
      tile[d][ts + 4 * i + 3] = v.w;
    }
  }
  __syncthreads();
  {
    const int t = tid >> 2;
    const int dseg = (tid & 3) * 16;
    uint32_t hw[8], lw[8];
    #pragma unroll
    for (int jj = 0; jj < 8; ++jj) {
      short h0, l0, h1, l1;
      split_bf16(tile[dseg + 2 * jj + 0][t], h0, l0);
      split_bf16(tile[dseg + 2 * jj + 1][t], h1, l1);
      hw[jj] = (uint32_t)(uint16_t)h0 | ((uint32_t)(uint16_t)h1 << 16);
      lw[jj] = (uint32_t)(uint16_t)l0 | ((uint32_t)(uint16_t)l1 << 16);
    }
    unsigned short* orow = QT + ((size_t)bh * 1024 + t0 + t) * 128;
    uint4* oh = reinterpret_cast<uint4*>(orow + dseg);
    oh[0] = make_uint4(hw[0], hw[1], hw[2], hw[3]);
    oh[1] = make_uint4(hw[4], hw[5], hw[6], hw[7]);
    uint4* ol = reinterpret_cast<uint4*>(orow + 64 + dseg);
    ol[0] = make_uint4(lw[0], lw[1], lw[2], lw[3]);
    ol[1] = make_uint4(lw[4], lw[5], lw[6], lw[7]);
  }
}

// ---------------- kernel 0b: V fp32 -> bf16 (layout preserved), kills per-iter cvt in k2 ------
__global__ void k0b_vcast(const float* __restrict__ V, unsigned short* __restrict__ VB) {
  const size_t i = ((size_t)blockIdx.x * 256 + threadIdx.x) * 8;
  float4 a = *reinterpret_cast<const float4*>(V + i);
  float4 b = *reinterpret_cast<const float4*>(V + i + 4);
  short8 o;
  o[0] = cvt_bf16(a.x); o[1] = cvt_bf16(a.y); o[2] = cvt_bf16(a.z); o[3] = cvt_bf16(a.w);
  o[4] = cvt_bf16(b.x); o[5] = cvt_bf16(b.y); o[6] = cvt_bf16(b.z); o[7] = cvt_bf16(b.w);
  *reinterpret_cast<short8*>(VB + i) = o;
}

// ---------------- kernel 1: scores = K^T Q /8, mask, exp (no max), norm, write attn fp32 ------
// Main-loop QT loads now go through global_load_lds with a per-wave TRIPLE buffer and counted
// vmcnt(8/4/0): round-1 proved the per-nf L2 round-trip is not occupancy-hideable (VGPR-starved
// s/w pipeline); gll prefetch depth costs 0 VGPRs, so chunk n+2 streams while n computes.
// LDS chunk layout [c:rowbyte-quarter][seg][t]: gll dest = base + lane*16 linear (m104-safe);
// ds_read_b128 fragments hit 8 distinct rows across 8 independent 16B bank groups = BW-optimal.
// Epilogue: LDS-transposed attn store (1KB-contiguous dwordx4 per wave-instr), pool reused.
// grid (96 bh, 64 sblk): x = bh so same-bh blocks share one XCD's L2 (96 % 8 == 0).
__global__ __launch_bounds__(256, 3)
void k1_scores_softmax(const float* __restrict__ Kt, const int* __restrict__ masks,
                       const unsigned short* __restrict__ QT, float* __restrict__ attn) {
  const int bh = blockIdx.x;
  const int b = bh / 12;
  const int s0 = blockIdx.y * 16;
  const int tid = threadIdx.x;
  const int w = tid >> 6, lane = tid & 63;
  const int q = lane >> 4, l15 = lane & 15;

  __shared__ __align__(16) char pool[49152];   // 4 waves x 3 bufs x 4KB; reused as xpose later
  __shared__ float redsum[4][16];

  // A = K^T fragments: A[m=s][k=d], lane row m=l15, k = kk*32 + q*8 + j. Loaded once, split.
  short8 ahi[2], alo[2];
  {
    const float* Kp = Kt + (size_t)bh * 65536 + s0 + l15;
    #pragma unroll
    for (int kk = 0; kk < 2; ++kk)
      #pragma unroll
      for (int j = 0; j < 8; ++j) {
        short h, l;
        split_bf16(Kp[(size_t)(kk * 32 + q * 8 + j) * 1024], h, l);
        ahi[kk][j] = h; alo[kk][j] = l;
      }
  }

  // Pre-read mask bits for this lane's 16 t values.
  const int* mrow = masks + b * 1024;
  uint32_t mkbits = 0;
  #pragma unroll
  for (int nf = 0; nf < 16; ++nf)
    mkbits |= (mrow[w * 256 + nf * 16 + l15] != 0 ? 1u : 0u) << nf;

  floatx4 acc[16];
  #pragma unroll
  for (int i = 0; i < 16; ++i) acc[i] = (floatx4){0.f, 0.f, 0.f, 0.f};

  // Staging geometry: chunk n = 16 t-rows (256B each) of this wave's t-range.
  // gll instr c (c=0..3 covers row bytes c*64..c*64+63): lane i -> t=(i&15), seg=(i>>4).
  // LDS linear: chunkbase + c*1024 + i*16  == [c][seg][t] with t*16 + seg*256.
  const unsigned char* QTbytes = (const unsigned char*)(QT + (size_t)bh * 131072);
  const unsigned char* gl = QTbytes + ((size_t)(w * 256 + (lane & 15)) << 8) + ((lane >> 4) << 4);
  char* const wbase = pool + w * 12288;
  const int rdoff = q * 256 + l15 * 16;

  #define STAGE_CHUNK(bufi, n)                                                   \
    {                                                                            \
      const unsigned char* s_ = gl + (n) * 4096;                                 \
      char* d_ = wbase + (bufi) * 4096;                                          \
      gll16(s_, d_); gll16(s_ + 64, d_ + 1024);                                  \
      gll16(s_ + 128, d_ + 2048); gll16(s_ + 192, d_ + 3072);                    \
    }

  STAGE_CHUNK(0, 0)
  STAGE_CHUNK(1, 1)

  #pragma unroll
  for (int nf = 0; nf < 16; ++nf) {
    if (nf + 2 < 16) STAGE_CHUNK((nf + 2) % 3, nf + 2)
    if (nf < 14)       asm volatile("s_waitcnt vmcnt(8)" ::: "memory");
    else if (nf == 14) asm volatile("s_waitcnt vmcnt(4)" ::: "memory");
    else               asm volatile("s_waitcnt vmcnt(0)" ::: "memory");
    const char* sb = wbase + (nf % 3) * 4096;
    #pragma unroll
    for (int kk = 0; kk < 2; ++kk) {
      short8 bhh = *reinterpret_cast<const short8*>(sb + kk * 1024 + rdoff);        // Q hi
      short8 bll = *reinterpret_cast<const short8*>(sb + (2 + kk) * 1024 + rdoff);  // Q lo
      acc[nf] = __builtin_amdgcn_mfma_f32_16x16x32_bf16(ahi[kk], bhh, acc[nf], 0, 0, 0);
      acc[nf] = __builtin_amdgcn_mfma_f32_16x16x32_bf16(alo[kk], bhh, acc[nf], 0, 0, 0);
      acc[nf] = __builtin_amdgcn_mfma_f32_16x16x32_bf16(ahi[kk], bll, acc[nf], 0, 0, 0);
    }
  }
  #undef STAGE_CHUNK

  // exp + per-row sum. C/D layout: col t = l15, row s_local = q*4 + r.
  float sm[4] = {0.f, 0.f, 0.f, 0.f};
  #pragma unroll
  for (int nf = 0; nf < 16; ++nf) {
    const bool mk = (mkbits >> nf) & 1u;
    #pragma unroll
    for (int r = 0; r < 4; ++r) {
      float e = mk ? __expf(acc[nf][r] * 0.125f) : 0.0f;
      acc[nf][r] = e;
      sm[r] += e;
    }
  }
  #pragma unroll
  for (int r = 0; r < 4; ++r)
    #pragma unroll
    for (int off = 1; off < 16; off <<= 1)
      sm[r] += __shfl_xor(sm[r], off, 16);

  if (l15 == 0) {
    #pragma unroll
    for (int r = 0; r < 4; ++r) redsum[w][q * 4 + r] = sm[r];
  }
  __syncthreads();
  float inv[4];
  #pragma unroll
  for (int r = 0; r < 4; ++r)
    inv[r] = 1.0f / (redsum[0][q * 4 + r] + redsum[1][q * 4 + r] +
                     redsum[2][q * 4 + r] + redsum[3][q * 4 + r]);

  // ---- LDS-transposed store: two t-halves of 512, each staged as [16 s][516] fp32 ----
  float (*xpose)[516] = reinterpret_cast<float (*)[516]>(pool);   // 33.0 KB <= pool
  float* arow = attn + (size_t)bh * 1048576 + (size_t)s0 * 1024;
  #pragma unroll
  for (int half = 0; half < 2; ++half) {
    __syncthreads();                 // pool free (main loop fully drained) / half reuse
    if ((w >> 1) == half) {          // waves owning this t-half dump their normalized tile
      const int wl = w & 1;
      #pragma unroll
      for (int nf = 0; nf < 16; ++nf)
        #pragma unroll
        for (int r = 0; r < 4; ++r)
          xpose[q * 4 + r][wl * 256 + nf * 16 + l15] = acc[nf][r] * inv[r];
    }
    __syncthreads();
    // all 4 waves store: wave w -> rows w*4..w*4+3; each instr = 64 lanes x float4 = 1KB contig
    #pragma unroll
    for (int rr = 0; rr < 4; ++rr) {
      const int row = w * 4 + rr;
      #pragma unroll
      for (int c = 0; c < 2; ++c) {
        float4 v = *reinterpret_cast<const float4*>(&xpose[row][c * 256 + lane * 4]);
        *reinterpret_cast<float4*>(arow + (size_t)row * 1024 + half * 512 + c * 256 + lane * 4) = v;
      }
    }
  }
}

// ---------------- kernel 2: context[d,t] = sum_s V[d,s] * attn[s,t] -> out[b][t][h*64+d] ------
// gll double-buffered staging of BOTH attn [32s][128t] fp32 tiles and V [64d][32s] bf16 chunks.
// Fixes round-2's flaw: prefetch loads were drained by the immediately-following barrier.
// Now: issue next-tile gll FIRST, then ds_read+MFMA on current tile (~400cy covers latency),
// then one barrier (drains gll, syncs buffer swap). V staged once per iter (4 gll total) vs
// 256 redundant 2KB-stride wave-loads. s-split over gridDim.z; z=1 -> partial P, k3 adds.
// grid (96 bh, 8 tblk, z): x = bh so blocks sharing attn/V slices land on one XCD.
__global__ __launch_bounds__(256, 4)
void k2_pv(const unsigned short* __restrict__ VB, const float* __restrict__ attn,
           float* __restrict__ out0, float* __restrict__ out1, int iters) {
  const int bh = blockIdx.x;
  const int b = bh / 12, h = bh % 12;
  const int t0 = blockIdx.y * 128;
  const int z = blockIdx.z;
  float* __restrict__ outp = (z == 0) ? out0 : out1;
  const int s_base = z * iters * 32;
  const int tid = threadIdx.x;
  const int wave = tid >> 6, lane = tid & 63;
  const int q = lane >> 4, l15 = lane & 15;

  __shared__ __align__(16) float att[2][32 * 128];      // 2 x 16KB, linear [s_local][t_local]
  __shared__ __align__(16) unsigned short Vt[2][2048];  // 2 x 4KB,  [d>>4][d&15][seg][8 bf16]

  const unsigned char* Ab = (const unsigned char*)(attn + (size_t)bh * 1048576 + t0);
  const unsigned char* VBb = (const unsigned char*)(VB + (size_t)bh * 65536);

  // attn tile: wave instr k (p = wave*4+k): rows 2p,2p+1; lane: s=2p+(lane>>5), 16B col (lane&31)
  const unsigned char* aSrc = Ab + (size_t)(8 * wave + (lane >> 5)) * 4096 + (lane & 31) * 16;
  // V chunk: instr per wave: d = wave*16 + (lane>>2), seg = lane&3 (16B = 8 bf16 = 8 s)
  const unsigned char* vSrc = VBb + (size_t)(wave * 16 + (lane >> 2)) * 2048 + (lane & 3) * 16;

  #define STAGE_TILE(bufi, it)                                                    \
    {                                                                             \
      const unsigned char* sa_ = aSrc + (size_t)(s_base + (it) * 32) * 4096;      \
      char* da_ = (char*)att[bufi] + wave * 4096;                                 \
      gll16(sa_, da_);           gll16(sa_ + 8192, da_ + 1024);                   \
      gll16(sa_ + 16384, da_ + 2048); gll16(sa_ + 24576, da_ + 3072);             \
      gll16(vSrc + (size_t)(s_base + (it) * 32) * 2, (char*)Vt[bufi] + wave * 1024); \
    }

  floatx4 acc[4][2];
  #pragma unroll
  for (int i = 0; i < 4; ++i)
    #pragma unroll
    for (int j = 0; j < 2; ++j) acc[i][j] = (floatx4){0.f, 0.f, 0.f, 0.f};

  STAGE_TILE(0, 0)
  asm volatile("s_waitcnt vmcnt(0)" ::: "memory");
  __syncthreads();

  int cur = 0;
  for (int it = 0; it < iters; ++it) {
    if (it + 1 < iters) STAGE_TILE(cur ^ 1, it + 1)   // in flight through this iter's compute

    // A = V fragments from LDS: d = mf*16+l15, s-seg = q. 8 rows/bank-group = BW-optimal b128.
    short8 va[4];
    #pragma unroll
    for (int mf = 0; mf < 4; ++mf)
      va[mf] = *reinterpret_cast<const short8*>((const char*)Vt[cur] + mf * 1024 + l15 * 64 + q * 16);

    // B = attn fragments from LDS: s_local = q*8+j, t_local = wave*32+nf*16+l15.
    short8 pa[2];
    const float* buf = att[cur];
    #pragma unroll
    for (int nf = 0; nf < 2; ++nf) {
      const int tl = wave * 32 + nf * 16 + l15;
      #pragma unroll
      for (int j = 0; j < 8; ++j)
        pa[nf][j] = cvt_bf16(buf[(q * 8 + j) * 128 + tl]);
    }

    #pragma unroll
    for (int mf = 0; mf < 4; ++mf)
      #pragma unroll
      for (int nf = 0; nf < 2; ++nf)
        acc[mf][nf] = __builtin_amdgcn_mfma_f32_16x16x32_bf16(va[mf], pa[nf], acc[mf][nf], 0, 0, 0);

    asm volatile("s_waitcnt vmcnt(0)" ::: "memory");  // next tile landed in LDS
    __syncthreads();                                  // all waves done reading att[cur]
    cur ^= 1;
  }
  #undef STAGE_TILE

  const int twave = t0 + wave * 32;
  #pragma unroll
  for (int mf = 0; mf < 4; ++mf)
    #pragma unroll
    for (int nf = 0; nf < 2; ++nf) {
      const int t = twave + nf * 16 + l15;
      const int d0 = mf * 16 + q * 4;                 // rows = q*4+r (consecutive d) -> float4
      float* op = outp + ((size_t)b * 1024 + t) * 768 + h * 64 + d0;
      *reinterpret_cast<floatx4*>(op) = acc[mf][nf];
    }
}

// ---------------- kernel 3: ctx += P (only when s-split is active) ----------------------------
__global__ void k3_add(float* __restrict__ ctx, const float* __restrict__ P) {
  const size_t i = ((size_t)blockIdx.x * 256 + threadIdx.x) * 4;
  float4 a = *reinterpret_cast<const float4*>(ctx + i);
  float4 p = *reinterpret_cast<const float4*>(P + i);
  a.x += p.x; a.y += p.y; a.z += p.z; a.w += p.w;
  *reinterpret_cast<float4*>(ctx + i) = a;
}

extern "C" void kernel_launch(void* const* d_in, const int* in_sizes, int n_in,
                              void* d_out, int out_size, void* d_ws, size_t ws_size,
                              hipStream_t stream) {
  const float* Q = (const float*)d_in[0];
  const float* K = (const float*)d_in[1];
  const float* V = (const float*)d_in[2];
  const int* masks = (const int*)d_in[3];
  float* ctx = (float*)d_out;                               // (8,1024,768) fp32
  float* attn = (float*)d_out + (size_t)8 * 1024 * 768;     // (8,12,1024,1024) fp32

  const size_t QT_BYTES = (size_t)96 * 1024 * 128 * 2;      // 25.2 MB
  const size_t VB_BYTES = (size_t)96 * 64 * 1024 * 2;       // 12.6 MB
  const size_t P_BYTES  = (size_t)8 * 1024 * 768 * 4;       // 25.2 MB
  unsigned short* QT = (unsigned short*)d_ws;
  unsigned short* VB = (unsigned short*)((char*)d_ws + QT_BYTES);
  float* P = (float*)((char*)d_ws + QT_BYTES + VB_BYTES);
  const bool split = ws_size >= QT_BYTES + VB_BYTES + P_BYTES;

  k0_qtranspose<<<dim3(16, 96), 256, 0, stream>>>(Q, QT);
  k0b_vcast<<<3072, 256, 0, stream>>>(V, VB);
  k1_scores_softmax<<<dim3(96, 64), 256, 0, stream>>>(K, masks, QT, attn);
  if (split) {
    k2_pv<<<dim3(96, 8, 2), 256, 0, stream>>>(VB, attn, ctx, P, 16);
    k3_add<<<6144, 256, 0, stream>>>(ctx, P);
  } else {
    k2_pv<<<dim3(96, 8, 1), 256, 0, stream>>>(VB, attn, ctx, ctx, 32);
  }
}

// Round 4
// 731.189 us; speedup vs baseline: 1.1965x; 1.0010x over previous
//
#include <hip/hip_runtime.h>
#include <stdint.h>

// Problem constants: B=8, H=12, D=64, S=1024
// scores[b,h,s,t] = sum_d K[b,h,d,s]*Q[b,h,d,t] / 8 ; mask over t ; softmax over t
// context[b,h,d,t] = sum_s V[b,h,d,s]*attn[b,h,s,t] ; out0[b][t][h*64+d], out1 = attn

typedef __attribute__((ext_vector_type(8))) short short8;
typedef __attribute__((ext_vector_type(4))) float floatx4;

#define DEVINL __device__ __forceinline__

DEVINL uint32_t f2u(float x) { union { float f; uint32_t u; } c; c.f = x; return c.u; }
DEVINL float u2f(uint32_t u) { union { uint32_t u; float f; } c; c.u = u; return c.f; }

// RNE fp32 -> bf16
DEVINL short cvt_bf16(float x) {
  uint32_t u = f2u(x);
  uint32_t r = u + 0x7FFFu + ((u >> 16) & 1u);
  return (short)(r >> 16);
}

// Split fp32 x into bf16 hi (RNE) and bf16 lo = RNE(x - hi). hi+lo == x to ~2^-17 rel.
DEVINL void split_bf16(float x, short &hi, short &lo) {
  uint32_t u = f2u(x);
  uint32_t r = u + 0x7FFFu + ((u >> 16) & 1u);
  hi = (short)(r >> 16);
  float hf = u2f(r & 0xFFFF0000u);
  float lf = x - hf;
  uint32_t v = f2u(lf);
  uint32_t r2 = v + 0x7FFFu + ((v >> 16) & 1u);
  lo = (short)(r2 >> 16);
}

// async global->LDS, 16B per lane. Dest must be wave-uniform base; HW writes lane i at base+i*16.
typedef const __attribute__((address_space(1))) unsigned int gas_u32;
typedef __attribute__((address_space(3))) unsigned int las_u32;
DEVINL void gll16(const void* g, void* l) {
  __builtin_amdgcn_global_load_lds((gas_u32*)g, (las_u32*)l, 16, 0, 0);
}

// ---------------- kernel 0: Q[bh][d][t] fp32 -> QT[bh][t][{hi:64, lo:64}] bf16 ----------------
__global__ void k0_qtranspose(const float* __restrict__ Q, unsigned short* __restrict__ QT) {
  const int bh = blockIdx.y;
  const int t0 = blockIdx.x * 64;
  const int tid = threadIdx.x;
  __shared__ float tile[64][65];   // stride 65: only 2-way bank aliasing (free per m136)
  {
    const int d = tid >> 2;
    const int ts = (tid & 3) * 16;
    const float* src = Q + ((size_t)bh * 64 + d) * 1024 + t0 + ts;
    #pragma unroll
    for (int i = 0; i < 4; ++i) {
      float4 v = reinterpret_cast<const float4*>(src)[i];
      tile[d][ts + 4 * i + 0] = v.x;
      tile[d][ts + 4 * i + 1] = v.y;
      tile[d][ts + 4 * i + 2] = v.z;
      tile[d][ts + 4 * i + 3] = v.w;
    }
  }
  __syncthreads();
  {
    const int t = tid >> 2;
    const int dseg = (tid & 3) * 16;
    uint32_t hw[8], lw[8];
    #pragma unroll
    for (int jj = 0; jj < 8; ++jj) {
      short h0, l0, h1, l1;
      split_bf16(tile[dseg + 2 * jj + 0][t], h0, l0);
      split_bf16(tile[dseg + 2 * jj + 1][t], h1, l1);
      hw[jj] = (uint32_t)(uint16_t)h0 | ((uint32_t)(uint16_t)h1 << 16);
      lw[jj] = (uint32_t)(uint16_t)l0 | ((uint32_t)(uint16_t)l1 << 16);
    }
    unsigned short* orow = QT + ((size_t)bh * 1024 + t0 + t) * 128;
    uint4* oh = reinterpret_cast<uint4*>(orow + dseg);
    oh[0] = make_uint4(hw[0], hw[1], hw[2], hw[3]);
    oh[1] = make_uint4(hw[4], hw[5], hw[6], hw[7]);
    uint4* ol = reinterpret_cast<uint4*>(orow + 64 + dseg);
    ol[0] = make_uint4(lw[0], lw[1], lw[2], lw[3]);
    ol[1] = make_uint4(lw[4], lw[5], lw[6], lw[7]);
  }
}

// ---------------- kernel 0b: V fp32 -> bf16 (layout preserved), kills per-iter cvt in k2 ------
__global__ void k0b_vcast(const float* __restrict__ V, unsigned short* __restrict__ VB) {
  const size_t i = ((size_t)blockIdx.x * 256 + threadIdx.x) * 8;
  float4 a = *reinterpret_cast<const float4*>(V + i);
  float4 b = *reinterpret_cast<const float4*>(V + i + 4);
  short8 o;
  o[0] = cvt_bf16(a.x); o[1] = cvt_bf16(a.y); o[2] = cvt_bf16(a.z); o[3] = cvt_bf16(a.w);
  o[4] = cvt_bf16(b.x); o[5] = cvt_bf16(b.y); o[6] = cvt_bf16(b.z); o[7] = cvt_bf16(b.w);
  *reinterpret_cast<short8*>(VB + i) = o;
}

// ---------------- kernel 1: scores = K^T Q /8, mask, exp (no max), norm, write attn fp32 ------
// Per-wave TRIPLE-buffered global_load_lds staging of QT chunks, counted vmcnt(8/4/0); no
// barriers in the main loop (each wave reads only its own staging area), so nothing drains the
// queue. Epilogue: LDS-transposed attn store (1KB-contiguous dwordx4 per wave-instr).
// grid (96 bh, 64 sblk): x = bh so same-bh blocks share one XCD's L2 (96 % 8 == 0).
__global__ __launch_bounds__(256, 3)
void k1_scores_softmax(const float* __restrict__ Kt, const int* __restrict__ masks,
                       const unsigned short* __restrict__ QT, float* __restrict__ attn) {
  const int bh = blockIdx.x;
  const int b = bh / 12;
  const int s0 = blockIdx.y * 16;
  const int tid = threadIdx.x;
  const int w = tid >> 6, lane = tid & 63;
  const int q = lane >> 4, l15 = lane & 15;

  __shared__ __align__(16) char pool[49152];   // 4 waves x 3 bufs x 4KB; reused as xpose later
  __shared__ float redsum[4][16];

  // A = K^T fragments: A[m=s][k=d], lane row m=l15, k = kk*32 + q*8 + j. Loaded once, split.
  short8 ahi[2], alo[2];
  {
    const float* Kp = Kt + (size_t)bh * 65536 + s0 + l15;
    #pragma unroll
    for (int kk = 0; kk < 2; ++kk)
      #pragma unroll
      for (int j = 0; j < 8; ++j) {
        short h, l;
        split_bf16(Kp[(size_t)(kk * 32 + q * 8 + j) * 1024], h, l);
        ahi[kk][j] = h; alo[kk][j] = l;
      }
  }

  // Pre-read mask bits for this lane's 16 t values.
  const int* mrow = masks + b * 1024;
  uint32_t mkbits = 0;
  #pragma unroll
  for (int nf = 0; nf < 16; ++nf)
    mkbits |= (mrow[w * 256 + nf * 16 + l15] != 0 ? 1u : 0u) << nf;

  floatx4 acc[16];
  #pragma unroll
  for (int i = 0; i < 16; ++i) acc[i] = (floatx4){0.f, 0.f, 0.f, 0.f};

  // Staging geometry: chunk n = 16 t-rows (256B each) of this wave's t-range.
  // gll instr c (c=0..3 covers row bytes c*64..c*64+63): lane i -> t=(i&15), seg=(i>>4).
  // LDS linear: chunkbase + c*1024 + i*16  == [c][seg][t] with t*16 + seg*256.
  const unsigned char* QTbytes = (const unsigned char*)(QT + (size_t)bh * 131072);
  const unsigned char* gl = QTbytes + ((size_t)(w * 256 + (lane & 15)) << 8) + ((lane >> 4) << 4);
  char* const wbase = pool + w * 12288;
  const int rdoff = q * 256 + l15 * 16;

  #define STAGE_CHUNK(bufi, n)                                                   \
    {                                                                            \
      const unsigned char* s_ = gl + (n) * 4096;                                 \
      char* d_ = wbase + (bufi) * 4096;                                          \
      gll16(s_, d_); gll16(s_ + 64, d_ + 1024);                                  \
      gll16(s_ + 128, d_ + 2048); gll16(s_ + 192, d_ + 3072);                    \
    }

  STAGE_CHUNK(0, 0)
  STAGE_CHUNK(1, 1)

  #pragma unroll
  for (int nf = 0; nf < 16; ++nf) {
    if (nf + 2 < 16) STAGE_CHUNK((nf + 2) % 3, nf + 2)
    if (nf < 14)       asm volatile("s_waitcnt vmcnt(8)" ::: "memory");
    else if (nf == 14) asm volatile("s_waitcnt vmcnt(4)" ::: "memory");
    else               asm volatile("s_waitcnt vmcnt(0)" ::: "memory");
    const char* sb = wbase + (nf % 3) * 4096;
    #pragma unroll
    for (int kk = 0; kk < 2; ++kk) {
      short8 bhh = *reinterpret_cast<const short8*>(sb + kk * 1024 + rdoff);        // Q hi
      short8 bll = *reinterpret_cast<const short8*>(sb + (2 + kk) * 1024 + rdoff);  // Q lo
      acc[nf] = __builtin_amdgcn_mfma_f32_16x16x32_bf16(ahi[kk], bhh, acc[nf], 0, 0, 0);
      acc[nf] = __builtin_amdgcn_mfma_f32_16x16x32_bf16(alo[kk], bhh, acc[nf], 0, 0, 0);
      acc[nf] = __builtin_amdgcn_mfma_f32_16x16x32_bf16(ahi[kk], bll, acc[nf], 0, 0, 0);
    }
  }
  #undef STAGE_CHUNK

  // exp + per-row sum. C/D layout: col t = l15, row s_local = q*4 + r.
  float sm[4] = {0.f, 0.f, 0.f, 0.f};
  #pragma unroll
  for (int nf = 0; nf < 16; ++nf) {
    const bool mk = (mkbits >> nf) & 1u;
    #pragma unroll
    for (int r = 0; r < 4; ++r) {
      float e = mk ? __expf(acc[nf][r] * 0.125f) : 0.0f;
      acc[nf][r] = e;
      sm[r] += e;
    }
  }
  #pragma unroll
  for (int r = 0; r < 4; ++r)
    #pragma unroll
    for (int off = 1; off < 16; off <<= 1)
      sm[r] += __shfl_xor(sm[r], off, 16);

  if (l15 == 0) {
    #pragma unroll
    for (int r = 0; r < 4; ++r) redsum[w][q * 4 + r] = sm[r];
  }
  __syncthreads();
  float inv[4];
  #pragma unroll
  for (int r = 0; r < 4; ++r)
    inv[r] = 1.0f / (redsum[0][q * 4 + r] + redsum[1][q * 4 + r] +
                     redsum[2][q * 4 + r] + redsum[3][q * 4 + r]);

  // ---- LDS-transposed store: two t-halves of 512, each staged as [16 s][516] fp32 ----
  float (*xpose)[516] = reinterpret_cast<float (*)[516]>(pool);   // 33.0 KB <= pool
  float* arow = attn + (size_t)bh * 1048576 + (size_t)s0 * 1024;
  #pragma unroll
  for (int half = 0; half < 2; ++half) {
    __syncthreads();                 // pool free (main loop fully drained) / half reuse
    if ((w >> 1) == half) {          // waves owning this t-half dump their normalized tile
      const int wl = w & 1;
      #pragma unroll
      for (int nf = 0; nf < 16; ++nf)
        #pragma unroll
        for (int r = 0; r < 4; ++r)
          xpose[q * 4 + r][wl * 256 + nf * 16 + l15] = acc[nf][r] * inv[r];
    }
    __syncthreads();
    // all 4 waves store: wave w -> rows w*4..w*4+3; each instr = 64 lanes x float4 = 1KB contig
    #pragma unroll
    for (int rr = 0; rr < 4; ++rr) {
      const int row = w * 4 + rr;
      #pragma unroll
      for (int c = 0; c < 2; ++c) {
        float4 v = *reinterpret_cast<const float4*>(&xpose[row][c * 256 + lane * 4]);
        *reinterpret_cast<float4*>(arow + (size_t)row * 1024 + half * 512 + c * 256 + lane * 4) = v;
      }
    }
  }
}

// ---------------- kernel 2: context[d,t] = sum_s V[d,s] * attn[s,t] -> out[b][t][h*64+d] ------
// TRUE 2-deep pipeline this round. Round-3's flaw: __syncthreads() makes hipcc emit
// s_waitcnt vmcnt(0) before s_barrier, force-draining the just-issued prefetch every iter
// (pipeline depth 0). Fix: raw s_barrier + explicit counted vmcnt(5) (5 gll/wave/tile;
// tiles it,it+1 outstanding=10 -> retire tile it only). Schedule per iter:
//   vmcnt(5) ; s_barrier ; compute buf[cur] ; s_barrier ; STAGE(buf[cur], it+2)
// Raw barrier is safe: ds_read results are consumed by MFMAs (compiler lgkmcnt) pre-barrier.
// attn LDS tile is bank-conflict-fixed via pre-swizzled gll SOURCE (dest stays linear, m104):
// LDS[s][t] holds att[s][t ^ (((s>>3)&1)<<4)]; column reads use tl ^ ((q&1)<<4) -> 2-way = free.
// grid (96 bh, 8 tblk, z): x = bh so blocks sharing attn/V slices land on one XCD.
__global__ __launch_bounds__(256, 4)
void k2_pv(const unsigned short* __restrict__ VB, const float* __restrict__ attn,
           float* __restrict__ out0, float* __restrict__ out1, int iters) {
  const int bh = blockIdx.x;
  const int b = bh / 12, h = bh % 12;
  const int t0 = blockIdx.y * 128;
  const int z = blockIdx.z;
  float* __restrict__ outp = (z == 0) ? out0 : out1;
  const int s_base = z * iters * 32;
  const int tid = threadIdx.x;
  const int wave = tid >> 6, lane = tid & 63;
  const int q = lane >> 4, l15 = lane & 15;

  __shared__ __align__(16) float att[2][32 * 128];      // 2 x 16KB, [s_local][t_local] (swz)
  __shared__ __align__(16) unsigned short Vt[2][2048];  // 2 x 4KB,  [d>>4][d&15][seg][8 bf16]

  const unsigned char* Ab = (const unsigned char*)(attn + (size_t)bh * 1048576 + t0);
  const unsigned char* VBb = (const unsigned char*)(VB + (size_t)bh * 65536);

  // attn tile: instr k (p = wave*4+k): rows 2p,2p+1; lane: s = 2p+(lane>>5).
  // Source 16B-granule column is PRE-SWIZZLED by (wave&1)<<2 (s>>3 == wave for staged rows),
  // so LDS[s][g] = att[s][g ^ (((s>>3)&1)<<2)] with a linear LDS dest.
  const unsigned char* aSrc = Ab + (size_t)(8 * wave + (lane >> 5)) * 4096 +
                              (((lane & 31) ^ ((wave & 1) << 2)) << 4);
  // V chunk: d = wave*16 + (lane>>2), seg = lane&3 (16B = 8 bf16 = 8 s)
  const unsigned char* vSrc = VBb + (size_t)(wave * 16 + (lane >> 2)) * 2048 + (lane & 3) * 16;

  #define STAGE_TILE(bufi, it)                                                    \
    {                                                                             \
      const unsigned char* sa_ = aSrc + (size_t)(s_base + (it) * 32) * 4096;      \
      char* da_ = (char*)att[bufi] + wave * 4096;                                 \
      gll16(sa_, da_);           gll16(sa_ + 8192, da_ + 1024);                   \
      gll16(sa_ + 16384, da_ + 2048); gll16(sa_ + 24576, da_ + 3072);             \
      gll16(vSrc + (size_t)(s_base + (it) * 32) * 2, (char*)Vt[bufi] + wave * 1024); \
    }

  floatx4 acc[4][2];
  #pragma unroll
  for (int i = 0; i < 4; ++i)
    #pragma unroll
    for (int j = 0; j < 2; ++j) acc[i][j] = (floatx4){0.f, 0.f, 0.f, 0.f};

  STAGE_TILE(0, 0)
  STAGE_TILE(1, 1)

  int cur = 0;
  for (int it = 0; it < iters; ++it) {
    if (it < iters - 1) asm volatile("s_waitcnt vmcnt(5)" ::: "memory");  // tile it landed
    else                asm volatile("s_waitcnt vmcnt(0)" ::: "memory");
    __builtin_amdgcn_s_barrier();   // all waves' tile-it gll done (each waited its own)

    // A = V fragments from LDS: d = mf*16+l15, s-seg = q. Contiguous 1KB b128 = optimal.
    short8 va[4];
    #pragma unroll
    for (int mf = 0; mf < 4; ++mf)
      va[mf] = *reinterpret_cast<const short8*>((const char*)Vt[cur] + mf * 1024 + l15 * 64 + q * 16);

    // B = attn fragments from LDS: s_local = q*8+j, t_local = wave*32+nf*16+l15 (de-swizzle).
    short8 pa[2];
    const float* buf = att[cur];
    #pragma unroll
    for (int nf = 0; nf < 2; ++nf) {
      const int tsw = (wave * 32 + nf * 16 + l15) ^ ((q & 1) << 4);
      #pragma unroll
      for (int j = 0; j < 8; ++j)
        pa[nf][j] = cvt_bf16(buf[(q * 8 + j) * 128 + tsw]);
    }

    #pragma unroll
    for (int mf = 0; mf < 4; ++mf)
      #pragma unroll
      for (int nf = 0; nf < 2; ++nf)
        acc[mf][nf] = __builtin_amdgcn_mfma_f32_16x16x32_bf16(va[mf], pa[nf], acc[mf][nf], 0, 0, 0);

    __builtin_amdgcn_s_barrier();   // all waves done reading buf[cur]
    if (it + 2 < iters) STAGE_TILE(cur, it + 2)   // overwrite freed buffer; stays in flight
    cur ^= 1;
  }
  #undef STAGE_TILE

  const int twave = t0 + wave * 32;
  #pragma unroll
  for (int mf = 0; mf < 4; ++mf)
    #pragma unroll
    for (int nf = 0; nf < 2; ++nf) {
      const int t = twave + nf * 16 + l15;
      const int d0 = mf * 16 + q * 4;                 // rows = q*4+r (consecutive d) -> float4
      float* op = outp + ((size_t)b * 1024 + t) * 768 + h * 64 + d0;
      *reinterpret_cast<floatx4*>(op) = acc[mf][nf];
    }
}

// ---------------- kernel 3: ctx += P (only when s-split is active) ----------------------------
__global__ void k3_add(float* __restrict__ ctx, const float* __restrict__ P) {
  const size_t i = ((size_t)blockIdx.x * 256 + threadIdx.x) * 4;
  float4 a = *reinterpret_cast<const float4*>(ctx + i);
  float4 p = *reinterpret_cast<const float4*>(P + i);
  a.x += p.x; a.y += p.y; a.z += p.z; a.w += p.w;
  *reinterpret_cast<float4*>(ctx + i) = a;
}

extern "C" void kernel_launch(void* const* d_in, const int* in_sizes, int n_in,
                              void* d_out, int out_size, void* d_ws, size_t ws_size,
                              hipStream_t stream) {
  const float* Q = (const float*)d_in[0];
  const float* K = (const float*)d_in[1];
  const float* V = (const float*)d_in[2];
  const int* masks = (const int*)d_in[3];
  float* ctx = (float*)d_out;                               // (8,1024,768) fp32
  float* attn = (float*)d_out + (size_t)8 * 1024 * 768;     // (8,12,1024,1024) fp32

  const size_t QT_BYTES = (size_t)96 * 1024 * 128 * 2;      // 25.2 MB
  const size_t VB_BYTES = (size_t)96 * 64 * 1024 * 2;       // 12.6 MB
  const size_t P_BYTES  = (size_t)8 * 1024 * 768 * 4;       // 25.2 MB
  unsigned short* QT = (unsigned short*)d_ws;
  unsigned short* VB = (unsigned short*)((char*)d_ws + QT_BYTES);
  float* P = (float*)((char*)d_ws + QT_BYTES + VB_BYTES);
  const bool split = ws_size >= QT_BYTES + VB_BYTES + P_BYTES;

  k0_qtranspose<<<dim3(16, 96), 256, 0, stream>>>(Q, QT);
  k0b_vcast<<<3072, 256, 0, stream>>>(V, VB);
  k1_scores_softmax<<<dim3(96, 64), 256, 0, stream>>>(K, masks, QT, attn);
  if (split) {
    k2_pv<<<dim3(96, 8, 2), 256, 0, stream>>>(VB, attn, ctx, P, 16);
    k3_add<<<6144, 256, 0, stream>>>(ctx, P);
  } else {
    k2_pv<<<dim3(96, 8, 1), 256, 0, stream>>>(VB, attn, ctx, ctx, 32);
  }
}

// Round 5
// 675.284 us; speedup vs baseline: 1.2956x; 1.0828x over previous
//
#include <hip/hip_runtime.h>
#include <stdint.h>

// Problem constants: B=8, H=12, D=64, S=1024
// scores[b,h,s,t] = sum_d K[b,h,d,s]*Q[b,h,d,t] / 8 ; mask over t ; softmax over t
// context[b,h,d,t] = sum_s V[b,h,d,s]*attn[b,h,s,t] ; out0[b][t][h*64+d], out1 = attn

typedef __attribute__((ext_vector_type(8))) short short8;
typedef __attribute__((ext_vector_type(4))) float floatx4;

#define DEVINL __device__ __forceinline__

DEVINL uint32_t f2u(float x) { union { float f; uint32_t u; } c; c.f = x; return c.u; }
DEVINL float u2f(uint32_t u) { union { uint32_t u; float f; } c; c.u = u; return c.f; }

// RNE fp32 -> bf16
DEVINL short cvt_bf16(float x) {
  uint32_t u = f2u(x);
  uint32_t r = u + 0x7FFFu + ((u >> 16) & 1u);
  return (short)(r >> 16);
}

// Split fp32 x into bf16 hi (RNE) and bf16 lo = RNE(x - hi). hi+lo == x to ~2^-17 rel.
DEVINL void split_bf16(float x, short &hi, short &lo) {
  uint32_t u = f2u(x);
  uint32_t r = u + 0x7FFFu + ((u >> 16) & 1u);
  hi = (short)(r >> 16);
  float hf = u2f(r & 0xFFFF0000u);
  float lf = x - hf;
  uint32_t v = f2u(lf);
  uint32_t r2 = v + 0x7FFFu + ((v >> 16) & 1u);
  lo = (short)(r2 >> 16);
}

// async global->LDS, 16B per lane. Dest must be wave-uniform base; HW writes lane i at base+i*16.
typedef const __attribute__((address_space(1))) unsigned int gas_u32;
typedef __attribute__((address_space(3))) unsigned int las_u32;
DEVINL void gll16(const void* g, void* l) {
  __builtin_amdgcn_global_load_lds((gas_u32*)g, (las_u32*)l, 16, 0, 0);
}

// ---------------- kernel 0: Q[bh][d][t] fp32 -> QT[bh][t][{hi:64, lo:64}] bf16 ----------------
__global__ void k0_qtranspose(const float* __restrict__ Q, unsigned short* __restrict__ QT) {
  const int bh = blockIdx.y;
  const int t0 = blockIdx.x * 64;
  const int tid = threadIdx.x;
  __shared__ float tile[64][65];   // stride 65: only 2-way bank aliasing (free per m136)
  {
    const int d = tid >> 2;
    const int ts = (tid & 3) * 16;
    const float* src = Q + ((size_t)bh * 64 + d) * 1024 + t0 + ts;
    #pragma unroll
    for (int i = 0; i < 4; ++i) {
      float4 v = reinterpret_cast<const float4*>(src)[i];
      tile[d][ts + 4 * i + 0] = v.x;
      tile[d][ts + 4 * i + 1] = v.y;
      tile[d][ts + 4 * i + 2] = v.z;
      tile[d][ts + 4 * i + 3] = v.w;
    }
  }
  __syncthreads();
  {
    const int t = tid >> 2;
    const int dseg = (tid & 3) * 16;
    uint32_t hw[8], lw[8];
    #pragma unroll
    for (int jj = 0; jj < 8; ++jj) {
      short h0, l0, h1, l1;
      split_bf16(tile[dseg + 2 * jj + 0][t], h0, l0);
      split_bf16(tile[dseg + 2 * jj + 1][t], h1, l1);
      hw[jj] = (uint32_t)(uint16_t)h0 | ((uint32_t)(uint16_t)h1 << 16);
      lw[jj] = (uint32_t)(uint16_t)l0 | ((uint32_t)(uint16_t)l1 << 16);
    }
    unsigned short* orow = QT + ((size_t)bh * 1024 + t0 + t) * 128;
    uint4* oh = reinterpret_cast<uint4*>(orow + dseg);
    oh[0] = make_uint4(hw[0], hw[1], hw[2], hw[3]);
    oh[1] = make_uint4(hw[4], hw[5], hw[6], hw[7]);
    uint4* ol = reinterpret_cast<uint4*>(orow + 64 + dseg);
    ol[0] = make_uint4(lw[0], lw[1], lw[2], lw[3]);
    ol[1] = make_uint4(lw[4], lw[5], lw[6], lw[7]);
  }
}

// ---------------- kernel 0b: V fp32 -> bf16 (layout preserved), kills per-iter cvt in k2 ------
__global__ void k0b_vcast(const float* __restrict__ V, unsigned short* __restrict__ VB) {
  const size_t i = ((size_t)blockIdx.x * 256 + threadIdx.x) * 8;
  float4 a = *reinterpret_cast<const float4*>(V + i);
  float4 b = *reinterpret_cast<const float4*>(V + i + 4);
  short8 o;
  o[0] = cvt_bf16(a.x); o[1] = cvt_bf16(a.y); o[2] = cvt_bf16(a.z); o[3] = cvt_bf16(a.w);
  o[4] = cvt_bf16(b.x); o[5] = cvt_bf16(b.y); o[6] = cvt_bf16(b.z); o[7] = cvt_bf16(b.w);
  *reinterpret_cast<short8*>(VB + i) = o;
}

// ---------------- kernel 1: scores = K^T Q /8, mask, exp (no max), norm, write attn fp32 ------
// v5: 32-s blocks (grid 96x32). Each staged 4KB QT chunk now feeds TWO 16-s subtiles:
// 24 MFMA per chunk vs 12, and the count of chunk-processings (vmcnt waits, ds_reads, glls)
// plus QT L2 re-streaming all HALVE (1.5 GB -> 750 MB). MFMA/exp/store totals unchanged.
// acc[2][16] = 128 VGPR -> launch_bounds(256,2); k1 proved TLP-insensitive in round 1, and
// latency hiding comes from the 2-chunk-deep gll prefetch (unchanged), not wave count.
// Epilogue: LDS-transposed attn store (1KB-contiguous dwordx4), 4 phases (2 s-subtiles x 2 t-halves).
// grid (96 bh, 32 sblk): x = bh so same-bh blocks share one XCD's L2 (96 % 8 == 0).
__global__ __launch_bounds__(256, 2)
void k1_scores_softmax(const float* __restrict__ Kt, const int* __restrict__ masks,
                       const unsigned short* __restrict__ QT, float* __restrict__ attn) {
  const int bh = blockIdx.x;
  const int b = bh / 12;
  const int s0 = blockIdx.y * 32;
  const int tid = threadIdx.x;
  const int w = tid >> 6, lane = tid & 63;
  const int q = lane >> 4, l15 = lane & 15;

  __shared__ __align__(16) char pool[49152];   // 4 waves x 3 bufs x 4KB; reused as xpose later
  __shared__ float redsum[4][32];

  // A = K^T fragments, 2 s-subtiles: A[m=s][k=d], lane row m = s0+ss*16+l15, k = kk*32+q*8+j.
  short8 ahi[2][2], alo[2][2];
  #pragma unroll
  for (int ss = 0; ss < 2; ++ss) {
    const float* Kp = Kt + (size_t)bh * 65536 + s0 + ss * 16 + l15;
    #pragma unroll
    for (int kk = 0; kk < 2; ++kk)
      #pragma unroll
      for (int j = 0; j < 8; ++j) {
        short h, l;
        split_bf16(Kp[(size_t)(kk * 32 + q * 8 + j) * 1024], h, l);
        ahi[ss][kk][j] = h; alo[ss][kk][j] = l;
      }
  }

  // Pre-read mask bits for this lane's 16 t values (t-dependent only: shared by both subtiles).
  const int* mrow = masks + b * 1024;
  uint32_t mkbits = 0;
  #pragma unroll
  for (int nf = 0; nf < 16; ++nf)
    mkbits |= (mrow[w * 256 + nf * 16 + l15] != 0 ? 1u : 0u) << nf;

  floatx4 acc[2][16];
  #pragma unroll
  for (int ss = 0; ss < 2; ++ss)
    #pragma unroll
    for (int i = 0; i < 16; ++i) acc[ss][i] = (floatx4){0.f, 0.f, 0.f, 0.f};

  // Staging geometry: chunk n = 16 t-rows (256B each) of this wave's t-range.
  // gll instr c (c=0..3 covers row bytes c*64..c*64+63): lane i -> t=(i&15), seg=(i>>4).
  // LDS linear: chunkbase + c*1024 + i*16  == [c][seg][t] with t*16 + seg*256.
  const unsigned char* QTbytes = (const unsigned char*)(QT + (size_t)bh * 131072);
  const unsigned char* gl = QTbytes + ((size_t)(w * 256 + (lane & 15)) << 8) + ((lane >> 4) << 4);
  char* const wbase = pool + w * 12288;
  const int rdoff = q * 256 + l15 * 16;

  #define STAGE_CHUNK(bufi, n)                                                   \
    {                                                                            \
      const unsigned char* s_ = gl + (n) * 4096;                                 \
      char* d_ = wbase + (bufi) * 4096;                                          \
      gll16(s_, d_); gll16(s_ + 64, d_ + 1024);                                  \
      gll16(s_ + 128, d_ + 2048); gll16(s_ + 192, d_ + 3072);                    \
    }

  STAGE_CHUNK(0, 0)
  STAGE_CHUNK(1, 1)

  #pragma unroll
  for (int nf = 0; nf < 16; ++nf) {
    if (nf + 2 < 16) STAGE_CHUNK((nf + 2) % 3, nf + 2)
    if (nf < 14)       asm volatile("s_waitcnt vmcnt(8)" ::: "memory");
    else if (nf == 14) asm volatile("s_waitcnt vmcnt(4)" ::: "memory");
    else               asm volatile("s_waitcnt vmcnt(0)" ::: "memory");
    const char* sb = wbase + (nf % 3) * 4096;
    #pragma unroll
    for (int kk = 0; kk < 2; ++kk) {
      short8 bhh = *reinterpret_cast<const short8*>(sb + kk * 1024 + rdoff);        // Q hi
      short8 bll = *reinterpret_cast<const short8*>(sb + (2 + kk) * 1024 + rdoff);  // Q lo
      #pragma unroll
      for (int ss = 0; ss < 2; ++ss) {   // chunk data reused for both s-subtiles: 24 MFMA/chunk
        acc[ss][nf] = __builtin_amdgcn_mfma_f32_16x16x32_bf16(ahi[ss][kk], bhh, acc[ss][nf], 0, 0, 0);
        acc[ss][nf] = __builtin_amdgcn_mfma_f32_16x16x32_bf16(alo[ss][kk], bhh, acc[ss][nf], 0, 0, 0);
        acc[ss][nf] = __builtin_amdgcn_mfma_f32_16x16x32_bf16(ahi[ss][kk], bll, acc[ss][nf], 0, 0, 0);
      }
    }
  }
  #undef STAGE_CHUNK

  // exp + per-row sum. C/D layout: col t = l15, row s_local = ss*16 + q*4 + r.
  float sm[2][4] = {{0.f, 0.f, 0.f, 0.f}, {0.f, 0.f, 0.f, 0.f}};
  #pragma unroll
  for (int ss = 0; ss < 2; ++ss)
    #pragma unroll
    for (int nf = 0; nf < 16; ++nf) {
      const bool mk = (mkbits >> nf) & 1u;
      #pragma unroll
      for (int r = 0; r < 4; ++r) {
        float e = mk ? __expf(acc[ss][nf][r] * 0.125f) : 0.0f;
        acc[ss][nf][r] = e;
        sm[ss][r] += e;
      }
    }
  #pragma unroll
  for (int ss = 0; ss < 2; ++ss)
    #pragma unroll
    for (int r = 0; r < 4; ++r)
      #pragma unroll
      for (int off = 1; off < 16; off <<= 1)
        sm[ss][r] += __shfl_xor(sm[ss][r], off, 16);

  if (l15 == 0) {
    #pragma unroll
    for (int ss = 0; ss < 2; ++ss)
      #pragma unroll
      for (int r = 0; r < 4; ++r) redsum[w][ss * 16 + q * 4 + r] = sm[ss][r];
  }
  __syncthreads();
  float inv[2][4];
  #pragma unroll
  for (int ss = 0; ss < 2; ++ss)
    #pragma unroll
    for (int r = 0; r < 4; ++r) {
      const int rl = ss * 16 + q * 4 + r;
      inv[ss][r] = 1.0f / (redsum[0][rl] + redsum[1][rl] + redsum[2][rl] + redsum[3][rl]);
    }

  // ---- LDS-transposed store: 4 phases (ss x t-half), each staged as [16 s][516] fp32 ----
  float (*xpose)[516] = reinterpret_cast<float (*)[516]>(pool);   // 33.0 KB <= pool
  #pragma unroll
  for (int ss = 0; ss < 2; ++ss) {
    float* arow = attn + (size_t)bh * 1048576 + (size_t)(s0 + ss * 16) * 1024;
    #pragma unroll
    for (int half = 0; half < 2; ++half) {
      __syncthreads();                 // pool free (main loop fully drained) / phase reuse
      if ((w >> 1) == half) {          // waves owning this t-half dump their normalized tile
        const int wl = w & 1;
        #pragma unroll
        for (int nf = 0; nf < 16; ++nf)
          #pragma unroll
          for (int r = 0; r < 4; ++r)
            xpose[q * 4 + r][wl * 256 + nf * 16 + l15] = acc[ss][nf][r] * inv[ss][r];
      }
      __syncthreads();
      // all 4 waves store: wave w -> rows w*4..w*4+3; each instr = 64 lanes x float4 = 1KB contig
      #pragma unroll
      for (int rr = 0; rr < 4; ++rr) {
        const int row = w * 4 + rr;
        #pragma unroll
        for (int c = 0; c < 2; ++c) {
          float4 v = *reinterpret_cast<const float4*>(&xpose[row][c * 256 + lane * 4]);
          *reinterpret_cast<float4*>(arow + (size_t)row * 1024 + half * 512 + c * 256 + lane * 4) = v;
        }
      }
    }
  }
}

// ---------------- kernel 2: context[d,t] = sum_s V[d,s] * attn[s,t] -> out[b][t][h*64+d] ------
// UNCHANGED from round 4 (single-variable round; k2 assessed near its HBM floor).
// 2-deep pipeline: raw s_barrier + counted vmcnt(5); gll-staged attn (source-swizzled) + V.
// grid (96 bh, 8 tblk, z): x = bh so blocks sharing attn/V slices land on one XCD.
__global__ __launch_bounds__(256, 4)
void k2_pv(const unsigned short* __restrict__ VB, const float* __restrict__ attn,
           float* __restrict__ out0, float* __restrict__ out1, int iters) {
  const int bh = blockIdx.x;
  const int b = bh / 12, h = bh % 12;
  const int t0 = blockIdx.y * 128;
  const int z = blockIdx.z;
  float* __restrict__ outp = (z == 0) ? out0 : out1;
  const int s_base = z * iters * 32;
  const int tid = threadIdx.x;
  const int wave = tid >> 6, lane = tid & 63;
  const int q = lane >> 4, l15 = lane & 15;

  __shared__ __align__(16) float att[2][32 * 128];      // 2 x 16KB, [s_local][t_local] (swz)
  __shared__ __align__(16) unsigned short Vt[2][2048];  // 2 x 4KB,  [d>>4][d&15][seg][8 bf16]

  const unsigned char* Ab = (const unsigned char*)(attn + (size_t)bh * 1048576 + t0);
  const unsigned char* VBb = (const unsigned char*)(VB + (size_t)bh * 65536);

  // attn tile: instr k (p = wave*4+k): rows 2p,2p+1; lane: s = 2p+(lane>>5).
  // Source 16B-granule column is PRE-SWIZZLED by (wave&1)<<2 (s>>3 == wave for staged rows),
  // so LDS[s][g] = att[s][g ^ (((s>>3)&1)<<2)] with a linear LDS dest.
  const unsigned char* aSrc = Ab + (size_t)(8 * wave + (lane >> 5)) * 4096 +
                              (((lane & 31) ^ ((wave & 1) << 2)) << 4);
  // V chunk: d = wave*16 + (lane>>2), seg = lane&3 (16B = 8 bf16 = 8 s)
  const unsigned char* vSrc = VBb + (size_t)(wave * 16 + (lane >> 2)) * 2048 + (lane & 3) * 16;

  #define STAGE_TILE(bufi, it)                                                    \
    {                                                                             \
      const unsigned char* sa_ = aSrc + (size_t)(s_base + (it) * 32) * 4096;      \
      char* da_ = (char*)att[bufi] + wave * 4096;                                 \
      gll16(sa_, da_);           gll16(sa_ + 8192, da_ + 1024);                   \
      gll16(sa_ + 16384, da_ + 2048); gll16(sa_ + 24576, da_ + 3072);             \
      gll16(vSrc + (size_t)(s_base + (it) * 32) * 2, (char*)Vt[bufi] + wave * 1024); \
    }

  floatx4 acc[4][2];
  #pragma unroll
  for (int i = 0; i < 4; ++i)
    #pragma unroll
    for (int j = 0; j < 2; ++j) acc[i][j] = (floatx4){0.f, 0.f, 0.f, 0.f};

  STAGE_TILE(0, 0)
  STAGE_TILE(1, 1)

  int cur = 0;
  for (int it = 0; it < iters; ++it) {
    if (it < iters - 1) asm volatile("s_waitcnt vmcnt(5)" ::: "memory");  // tile it landed
    else                asm volatile("s_waitcnt vmcnt(0)" ::: "memory");
    __builtin_amdgcn_s_barrier();   // all waves' tile-it gll done (each waited its own)

    // A = V fragments from LDS: d = mf*16+l15, s-seg = q. Contiguous 1KB b128 = optimal.
    short8 va[4];
    #pragma unroll
    for (int mf = 0; mf < 4; ++mf)
      va[mf] = *reinterpret_cast<const short8*>((const char*)Vt[cur] + mf * 1024 + l15 * 64 + q * 16);

    // B = attn fragments from LDS: s_local = q*8+j, t_local = wave*32+nf*16+l15 (de-swizzle).
    short8 pa[2];
    const float* buf = att[cur];
    #pragma unroll
    for (int nf = 0; nf < 2; ++nf) {
      const int tsw = (wave * 32 + nf * 16 + l15) ^ ((q & 1) << 4);
      #pragma unroll
      for (int j = 0; j < 8; ++j)
        pa[nf][j] = cvt_bf16(buf[(q * 8 + j) * 128 + tsw]);
    }

    #pragma unroll
    for (int mf = 0; mf < 4; ++mf)
      #pragma unroll
      for (int nf = 0; nf < 2; ++nf)
        acc[mf][nf] = __builtin_amdgcn_mfma_f32_16x16x32_bf16(va[mf], pa[nf], acc[mf][nf], 0, 0, 0);

    __builtin_amdgcn_s_barrier();   // all waves done reading buf[cur]
    if (it + 2 < iters) STAGE_TILE(cur, it + 2)   // overwrite freed buffer; stays in flight
    cur ^= 1;
  }
  #undef STAGE_TILE

  const int twave = t0 + wave * 32;
  #pragma unroll
  for (int mf = 0; mf < 4; ++mf)
    #pragma unroll
    for (int nf = 0; nf < 2; ++nf) {
      const int t = twave + nf * 16 + l15;
      const int d0 = mf * 16 + q * 4;                 // rows = q*4+r (consecutive d) -> float4
      float* op = outp + ((size_t)b * 1024 + t) * 768 + h * 64 + d0;
      *reinterpret_cast<floatx4*>(op) = acc[mf][nf];
    }
}

// ---------------- kernel 3: ctx += P (only when s-split is active) ----------------------------
__global__ void k3_add(float* __restrict__ ctx, const float* __restrict__ P) {
  const size_t i = ((size_t)blockIdx.x * 256 + threadIdx.x) * 4;
  float4 a = *reinterpret_cast<const float4*>(ctx + i);
  float4 p = *reinterpret_cast<const float4*>(P + i);
  a.x += p.x; a.y += p.y; a.z += p.z; a.w += p.w;
  *reinterpret_cast<float4*>(ctx + i) = a;
}

extern "C" void kernel_launch(void* const* d_in, const int* in_sizes, int n_in,
                              void* d_out, int out_size, void* d_ws, size_t ws_size,
                              hipStream_t stream) {
  const float* Q = (const float*)d_in[0];
  const float* K = (const float*)d_in[1];
  const float* V = (const float*)d_in[2];
  const int* masks = (const int*)d_in[3];
  float* ctx = (float*)d_out;                               // (8,1024,768) fp32
  float* attn = (float*)d_out + (size_t)8 * 1024 * 768;     // (8,12,1024,1024) fp32

  const size_t QT_BYTES = (size_t)96 * 1024 * 128 * 2;      // 25.2 MB
  const size_t VB_BYTES = (size_t)96 * 64 * 1024 * 2;       // 12.6 MB
  const size_t P_BYTES  = (size_t)8 * 1024 * 768 * 4;       // 25.2 MB
  unsigned short* QT = (unsigned short*)d_ws;
  unsigned short* VB = (unsigned short*)((char*)d_ws + QT_BYTES);
  float* P = (float*)((char*)d_ws + QT_BYTES + VB_BYTES);
  const bool split = ws_size >= QT_BYTES + VB_BYTES + P_BYTES;

  k0_qtranspose<<<dim3(16, 96), 256, 0, stream>>>(Q, QT);
  k0b_vcast<<<3072, 256, 0, stream>>>(V, VB);
  k1_scores_softmax<<<dim3(96, 32), 256, 0, stream>>>(K, masks, QT, attn);
  if (split) {
    k2_pv<<<dim3(96, 8, 2), 256, 0, stream>>>(VB, attn, ctx, P, 16);
    k3_add<<<6144, 256, 0, stream>>>(ctx, P);
  } else {
    k2_pv<<<dim3(96, 8, 1), 256, 0, stream>>>(VB, attn, ctx, ctx, 32);
  }
}